// Round 1
// baseline (591.776 us; speedup 1.0000x reference)
//
#include <hip/hip_runtime.h>
#include <math.h>

#define ANUM 3
#define CNUM 3
#define BNUM 32
#define MNUM 16
#define CH 24   // ANUM*(5+CNUM)

__device__ __forceinline__ float wred(float v){
  #pragma unroll
  for (int off=32; off; off>>=1) v += __shfl_down(v, off, 64);
  return v;
}

__global__ __launch_bounds__(256) void kinit(float* acc, float* lsum){
  int i = threadIdx.x;
  if (i < 480) acc[i] = 0.f;
  if (i < 3) lsum[i] = 0.f;
}

__global__ __launch_bounds__(256) void k1_scan(
    const float* __restrict__ pred, const float* __restrict__ boxes,
    const int* __restrict__ labels, float* __restrict__ negvals,
    float* __restrict__ acc, int H, int W, int scale)
{
  const int b = blockIdx.y;
  const int N = H*W*ANUM;
  const int HW = H*W;
  const int n = blockIdx.x*256 + threadIdx.x;

  __shared__ float sbox[MNUM*4];
  __shared__ int slab[MNUM];
  if (threadIdx.x < MNUM*4) sbox[threadIdx.x] = boxes[b*MNUM*4 + threadIdx.x];
  else if (threadIdx.x < MNUM*5) slab[threadIdx.x - MNUM*4] = labels[b*MNUM + (threadIdx.x - MNUM*4)];
  __syncthreads();

  float f_pos=0.f, f_neg=0.f, f_obj=0.f, f_ce=0.f, f_sl1=0.f;

  if (n < N) {
    const int a = n % ANUM;
    const int w = (n/ANUM) % W;
    const int h = n/(ANUM*W);
    const float sz = (a==0)?0.08f:((a==1)?0.16f:0.28f);
    const float cx = ((float)w + 0.5f)/(float)W;
    const float cy = ((float)h + 0.5f)/(float)H;
    const float hs = sz*0.5f;
    const float ax0=cx-hs, ay0=cy-hs, ax1=cx+hs, ay1=cy+hs;
    const float areaA = (ax1-ax0)*(ay1-ay0);

    float best=-1.f; int midx=0;
    #pragma unroll
    for (int m=0;m<MNUM;m++){
      float bcx=sbox[4*m+0], bcy=sbox[4*m+1], bw=sbox[4*m+2], bh=sbox[4*m+3];
      float bx0=bcx-bw*0.5f, by0=bcy-bh*0.5f, bx1=bcx+bw*0.5f, by1=bcy+bh*0.5f;
      float iw=fminf(ax1,bx1)-fmaxf(ax0,bx0);
      float ih=fminf(ay1,by1)-fmaxf(ay0,by0);
      iw = fmaxf(iw, 0.f); ih = fmaxf(ih, 0.f);
      float inter=iw*ih;
      float areaB=(bx1-bx0)*(by1-by0);
      float iou = inter/(areaA+areaB-inter+1e-9f);
      if (iou > best){best=iou; midx=m;}
    }
    const bool pos = best >= 0.5f;
    const bool neg = best < 0.4f;

    const float* pb = pred + (size_t)b*CH*HW;
    const int pix = h*W + w;
    const int cb = a*8;
    const float obj = pb[(cb+4)*HW + pix];
    const float sp = log1pf(expf(-fabsf(obj)));
    const float obj_all = fmaxf(obj, 0.f) - (pos ? obj : 0.f) + sp;

    negvals[(size_t)b*N + n] = neg ? obj_all : -1.f;

    if (pos) {
      f_pos = 1.f; f_obj = obj_all;
      int ct = slab[midx] - 1;
      ct = ct < 0 ? 0 : (ct > CNUM-1 ? CNUM-1 : ct);
      float c0 = pb[(cb+5)*HW+pix];
      float c1 = pb[(cb+6)*HW+pix];
      float c2 = pb[(cb+7)*HW+pix];
      float mx = fmaxf(c0, fmaxf(c1, c2));
      float lse = mx + logf(expf(c0-mx)+expf(c1-mx)+expf(c2-mx));
      float csel = (ct==0)?c0:((ct==1)?c1:c2);
      f_ce = lse - csel;
      float mcx=sbox[4*midx+0], mcy=sbox[4*midx+1], mw=sbox[4*midx+2], mh=sbox[4*midx+3];
      float t0=(mcx-cx)/sz, t1=(mcy-cy)/sz, t2=logf(mw/sz), t3=logf(mh/sz);
      float l0=pb[(cb+0)*HW+pix], l1=pb[(cb+1)*HW+pix], l2=pb[(cb+2)*HW+pix], l3=pb[(cb+3)*HW+pix];
      float ssum=0.f, d;
      d=fabsf(l0-t0); ssum += (d<1.f)?(0.5f*d*d):(d-0.5f);
      d=fabsf(l1-t1); ssum += (d<1.f)?(0.5f*d*d):(d-0.5f);
      d=fabsf(l2-t2); ssum += (d<1.f)?(0.5f*d*d):(d-0.5f);
      d=fabsf(l3-t3); ssum += (d<1.f)?(0.5f*d*d):(d-0.5f);
      f_sl1 = ssum;
    } else if (neg) {
      f_neg = 1.f;
    }
  }

  __shared__ float red[5][4];
  const int lane = threadIdx.x & 63, wv = threadIdx.x >> 6;
  float vals[5] = {f_pos, f_neg, f_obj, f_ce, f_sl1};
  #pragma unroll
  for (int q=0;q<5;q++){
    float r = wred(vals[q]);
    if (lane==0) red[q][wv] = r;
  }
  __syncthreads();
  if (threadIdx.x==0){
    float* ag = acc + (scale*BNUM + b)*5;
    #pragma unroll
    for (int q=0;q<5;q++){
      float t = red[q][0]+red[q][1]+red[q][2]+red[q][3];
      if (t != 0.f) atomicAdd(&ag[q], t);
    }
  }
}

__global__ __launch_bounds__(256) void k2_select(
    const float* __restrict__ negvals, const float* __restrict__ acc,
    float* __restrict__ lsum)
{
  const int g = blockIdx.x;
  const int s = g >> 5;
  const int b = g & 31;
  const int N = (s==0) ? 76800 : ((s==1) ? 19200 : 4800);
  const size_t base = (s==0) ? 0
                    : ((s==1) ? (size_t)BNUM*76800
                              : (size_t)BNUM*(76800+19200));
  const float* seg = negvals + base + (size_t)b*N;

  const float* ag = acc + g*5;
  const float npos_f = ag[0], avail_f = ag[1];
  const int npos = (int)(npos_f + 0.5f);
  const int avail = (int)(avail_f + 0.5f);
  int k = (npos==0) ? (avail < 100 ? avail : 100)
                    : (3*npos < avail ? 3*npos : avail);

  __shared__ int hist[256];
  __shared__ unsigned int s_pref;
  __shared__ int s_kk;

  float selsum = 0.f; float nsel = 0.f;
  if (k > 0) {
    unsigned int prefix = 0, pmask = 0;
    int kk = k;
    for (int pass=0; pass<4; pass++){
      const int shift = 24 - 8*pass;
      hist[threadIdx.x] = 0;
      __syncthreads();
      for (int i=threadIdx.x; i<N; i+=256){
        float v = seg[i];
        if (v < 0.f) continue;
        unsigned int u = __float_as_uint(v);
        if ((u & pmask) == prefix) atomicAdd(&hist[(u>>shift)&255], 1);
      }
      __syncthreads();
      if (threadIdx.x==0){
        int cum=0, bin=255;
        for (int j=255;j>=0;j--){
          cum += hist[j];
          if (cum >= kk){ bin=j; kk -= (cum - hist[j]); break; }
        }
        s_pref = prefix | ((unsigned)bin << shift);
        s_kk = kk;
      }
      __syncthreads();
      prefix = s_pref; kk = s_kk;
      pmask |= (0xFFu << shift);
      __syncthreads();
    }
    const float thr = __uint_as_float(prefix);
    for (int i=threadIdx.x;i<N;i+=256){
      float v = seg[i];
      if (v >= thr){ selsum += v; nsel += 1.f; }
    }
  }

  __shared__ float red[2][4];
  const int lane = threadIdx.x & 63, wv = threadIdx.x >> 6;
  float r0 = wred(selsum), r1 = wred(nsel);
  if (lane==0){ red[0][wv]=r0; red[1][wv]=r1; }
  __syncthreads();
  if (threadIdx.x==0){
    float ss = red[0][0]+red[0][1]+red[0][2]+red[0][3];
    float ns = red[1][0]+red[1][1]+red[1][2]+red[1][3];
    float cnt = npos_f + ns;
    float lo = (cnt > 0.f) ? (ag[2] + ss)/cnt : 0.f;
    float lc = (npos > 0) ? ag[3]/npos_f : 0.f;
    float ll = (npos > 0) ? ag[4]/(npos_f*4.f) : 0.f;
    atomicAdd(&lsum[0], lo);
    atomicAdd(&lsum[1], lc);
    atomicAdd(&lsum[2], ll);
  }
}

__global__ __launch_bounds__(64) void kfin(const float* lsum, float* out){
  if (threadIdx.x==0){
    float lo = lsum[0]*(1.f/32.f);
    float lc = lsum[1]*(1.f/32.f);
    float ll = lsum[2]*(1.f/32.f);
    out[0]=lo; out[1]=lc; out[2]=ll; out[3]=lo+lc+ll;
  }
}

extern "C" void kernel_launch(void* const* d_in, const int* in_sizes, int n_in,
                              void* d_out, int out_size, void* d_ws, size_t ws_size,
                              hipStream_t stream)
{
  const float* pred0 = (const float*)d_in[0];
  const float* pred1 = (const float*)d_in[1];
  const float* pred2 = (const float*)d_in[2];
  const float* boxes = (const float*)d_in[6];
  const int*   labels = (const int*)d_in[7];
  float* out = (float*)d_out;

  float* negvals = (float*)d_ws;            // 3,225,600 floats
  float* acc  = negvals + 3225600;          // 96*5 floats
  float* lsum = acc + 480;                  // 3 floats

  kinit<<<1, 256, 0, stream>>>(acc, lsum);
  k1_scan<<<dim3(300,32), 256, 0, stream>>>(pred0, boxes, labels, negvals, acc, 160,160, 0);
  k1_scan<<<dim3(75,32),  256, 0, stream>>>(pred1, boxes, labels, negvals + (size_t)BNUM*76800, acc, 80,80, 1);
  k1_scan<<<dim3(19,32),  256, 0, stream>>>(pred2, boxes, labels, negvals + (size_t)BNUM*(76800+19200), acc, 40,40, 2);
  k2_select<<<96, 256, 0, stream>>>(negvals, acc, lsum);
  kfin<<<1, 64, 0, stream>>>(lsum, out);
}